// Round 7
// baseline (381.090 us; speedup 1.0000x reference)
//
#include <hip/hip_runtime.h>
#include <math.h>

#define TT 512
#define GG 3
#define HH 32
#define DD 128

typedef _Float16 half8 __attribute__((ext_vector_type(8)));
typedef float f32x4 __attribute__((ext_vector_type(4)));

__device__ __forceinline__ float fast_tanh(float x) {
  float e = __expf(2.0f * x);
  return 1.0f - 2.0f * __builtin_amdgcn_rcpf(1.0f + e);
}

__device__ __forceinline__ uint32_t pack_half2(float a, float b) {
  auto p = __builtin_amdgcn_cvt_pkrtz(a, b);   // __fp16 ext_vector(2)
  return __builtin_bit_cast(uint32_t, p);
}

// TWO 16-seq groups (same g) per block of 2 waves; wave w owns j-tile
// [16w,16w+16) for BOTH groups. Interleaving two independent recurrences in
// one wave fills the serial chain's latency (only 384 groups exist -> 0.75
// waves/SIMD; no TLP available, so ILP must come from within the wave).
// A-fragments and gate constants are shared (same g). One barrier per step.
__global__ __launch_bounds__(128) void gru_scan_mfma(
    const float* __restrict__ x, const float* __restrict__ W_ih,
    const float* __restrict__ W_hh, const float* __restrict__ b_ih,
    const float* __restrict__ b_hh, float* __restrict__ hout, int B) {
  const int tid = threadIdx.x;
  const int w = tid >> 6;      // j-tile of this wave
  const int lane = tid & 63;
  const int col = lane & 15;   // seq-in-group for B/C; m-row for A
  const int grp = lane >> 4;   // k-block for A/B; row-group for C
  const int nb2 = B / 32;
  const int g = blockIdx.x / nb2;
  const int b0 = (blockIdx.x % nb2) * 32;   // 32 seqs: group0 = +0..15, group1 = +16..31
  const float L2E = 1.44269504088896340736f;

  // ---- x staging: [group][seq][t], leading dim 513 (bank spread) ----
  __shared__ float xlds[2][16][TT + 1];
  // ---- double-buffered fp16 h: [buf][group][seq][16 words + 4 pad] ----
  __shared__ uint32_t hbuf[2][2][16][20];

#pragma unroll 4
  for (int i = tid; i < 2 * 16 * TT; i += 128) {
    int s2 = i >> 9, t = i & (TT - 1);
    xlds[s2 >> 4][s2 & 15][t] = x[((size_t)(b0 + s2) * TT + t) * GG + g];
  }

  // ---- A fragments for this wave's j-tile (pre-scaled for exp2), shared ----
  half8 Af[3];
  const float* Wg = W_hh + (size_t)g * 3 * HH * HH;
#pragma unroll
  for (int gam = 0; gam < 3; ++gam) {
    const float sc = (gam == 2) ? 2.0f * L2E : -L2E;
    const float* src = Wg + (size_t)(gam * 32 + w * 16 + col) * HH + grp * 8;
    half8 a;
#pragma unroll
    for (int i = 0; i < 8; ++i) a[i] = (_Float16)(src[i] * sc);
    Af[gam] = a;
  }

  // ---- per-lane gate constants for j = w*16 + grp*4 + r, shared ----
  float wiR[4], wiZ[4], wiN[4], bR[4], bZ[4], bN[4], bHN[4];
#pragma unroll
  for (int r = 0; r < 4; ++r) {
    int j = w * 16 + grp * 4 + r;
    wiR[r] = W_ih[g * 96 + j] * (-L2E);
    wiZ[r] = W_ih[g * 96 + 32 + j] * (-L2E);
    wiN[r] = W_ih[g * 96 + 64 + j] * (2.0f * L2E);
    bR[r] = (b_ih[g * 96 + j] + b_hh[g * 96 + j]) * (-L2E);
    bZ[r] = (b_ih[g * 96 + 32 + j] + b_hh[g * 96 + 32 + j]) * (-L2E);
    bN[r] = b_ih[g * 96 + 64 + j] * (2.0f * L2E);
    bHN[r] = b_hh[g * 96 + 64 + j] * (2.0f * L2E);
  }

  float hoA[4], hoB[4];
#pragma unroll
  for (int r = 0; r < 4; ++r) { hoA[r] = 0.0f; hoB[r] = 0.0f; }
  for (int i = tid; i < 2 * 2 * 16 * 20; i += 128) ((uint32_t*)hbuf)[i] = 0u;
  __syncthreads();

  const f32x4 zero = {0.f, 0.f, 0.f, 0.f};

#define GATES(Cr, Cz, Cn, xv, ho)                                              \
  _Pragma("unroll") for (int r = 0; r < 4; ++r) {                              \
    float pr = Cr[r] + fmaf(xv, wiR[r], bR[r]);                                \
    float rr = __builtin_amdgcn_rcpf(1.0f + __builtin_amdgcn_exp2f(pr));       \
    float pz = Cz[r] + fmaf(xv, wiZ[r], bZ[r]);                                \
    float zz = __builtin_amdgcn_rcpf(1.0f + __builtin_amdgcn_exp2f(pz));       \
    float tnv = Cn[r] + bHN[r];                                                \
    float pn = fmaf(rr, tnv, fmaf(xv, wiN[r], bN[r]));                         \
    float u = __builtin_amdgcn_rcpf(1.0f + __builtin_amdgcn_exp2f(pn));        \
    float nn = fmaf(-2.0f, u, 1.0f);                                          \
    ho[r] = fmaf(zz, ho[r] - nn, nn);                                          \
  }

#define GRU_STEP(SRC, DST, TCUR)                                               \
  {                                                                            \
    float xA = xlds[0][col][TCUR];                                             \
    float xB = xlds[1][col][TCUR];                                             \
    half8 BfA = *(const half8*)&hbuf[SRC][0][col][grp * 4];                    \
    half8 BfB = *(const half8*)&hbuf[SRC][1][col][grp * 4];                    \
    f32x4 CrA = __builtin_amdgcn_mfma_f32_16x16x32_f16(Af[0], BfA, zero, 0, 0, 0); \
    f32x4 CzA = __builtin_amdgcn_mfma_f32_16x16x32_f16(Af[1], BfA, zero, 0, 0, 0); \
    f32x4 CnA = __builtin_amdgcn_mfma_f32_16x16x32_f16(Af[2], BfA, zero, 0, 0, 0); \
    f32x4 CrB = __builtin_amdgcn_mfma_f32_16x16x32_f16(Af[0], BfB, zero, 0, 0, 0); \
    f32x4 CzB = __builtin_amdgcn_mfma_f32_16x16x32_f16(Af[1], BfB, zero, 0, 0, 0); \
    f32x4 CnB = __builtin_amdgcn_mfma_f32_16x16x32_f16(Af[2], BfB, zero, 0, 0, 0); \
    GATES(CrA, CzA, CnA, xA, hoA)                                              \
    GATES(CrB, CzB, CnB, xB, hoB)                                              \
    uint2 wA, wB;                                                              \
    wA.x = pack_half2(hoA[0], hoA[1]);                                         \
    wA.y = pack_half2(hoA[2], hoA[3]);                                         \
    wB.x = pack_half2(hoB[0], hoB[1]);                                         \
    wB.y = pack_half2(hoB[2], hoB[3]);                                         \
    *(uint2*)&hbuf[DST][0][col][w * 8 + grp * 2] = wA;                         \
    *(uint2*)&hbuf[DST][1][col][w * 8 + grp * 2] = wB;                         \
    __syncthreads();                                                           \
  }

#pragma unroll 1
  for (int t = 0; t < TT; t += 2) {
    GRU_STEP(0, 1, t)
    GRU_STEP(1, 0, t + 1)
  }
#undef GRU_STEP
#undef GATES

#pragma unroll
  for (int r = 0; r < 4; ++r) {
    int j = w * 16 + grp * 4 + r;
    hout[((size_t)(b0 + col) * GG + g) * HH + j] = hoA[r];
    hout[((size_t)(b0 + 16 + col) * GG + g) * HH + j] = hoB[r];
  }
}

// One block per b: query -> scores -> softmax -> weighted rep -> out row,
// then broadcast-write the row across all T positions (coalesced float4).
__global__ __launch_bounds__(256) void epilogue(
    const float* __restrict__ ctx, const float* __restrict__ hf,
    const float* __restrict__ Wq, const float* __restrict__ bq,
    const float* __restrict__ Ws, const float* __restrict__ bs,
    const float* __restrict__ Wo, const float* __restrict__ bo,
    const float* __restrict__ logT, float* __restrict__ out, int B) {
  const int b = blockIdx.x;
  const int tid = threadIdx.x;
  __shared__ float sc[DD];
  __shared__ float sw[HH];
  __shared__ float srow[DD];
  if (tid < DD) sc[tid] = ctx[(size_t)b * DD + tid];
  __syncthreads();
  if (tid < HH) {
    float q = bq[tid];
#pragma unroll 4
    for (int d = 0; d < DD; ++d) q = fmaf(sc[d], Wq[d * HH + tid], q);
    float h0 = hf[((size_t)b * 3 + 0) * HH + tid];
    float h1 = hf[((size_t)b * 3 + 1) * HH + tid];
    float h2 = hf[((size_t)b * 3 + 2) * HH + tid];
    float wsv = Ws[tid];
    float s0 = fast_tanh(h0 + q) * wsv;
    float s1 = fast_tanh(h1 + q) * wsv;
    float s2 = fast_tanh(h2 + q) * wsv;
#pragma unroll
    for (int off = 16; off >= 1; off >>= 1) {
      s0 += __shfl_xor(s0, off, 32);
      s1 += __shfl_xor(s1, off, 32);
      s2 += __shfl_xor(s2, off, 32);
    }
    float bsv = bs[0];
    float tmp = fmaxf(__expf(logT[0]), 0.1f);
    float inv = 1.0f / tmp;
    s0 = (s0 + bsv) * inv; s1 = (s1 + bsv) * inv; s2 = (s2 + bsv) * inv;
    float m = fmaxf(s0, fmaxf(s1, s2));
    float e0 = __expf(s0 - m), e1 = __expf(s1 - m), e2 = __expf(s2 - m);
    float den = 1.0f / (e0 + e1 + e2);
    float a0 = e0 * den, a1 = e1 * den, a2 = e2 * den;
    sw[tid] = a0 * h0 + a1 * h1 + a2 * h2;
    if (tid == 0) {
      size_t aoff = (size_t)B * TT * DD + (size_t)b * 3;
      out[aoff] = a0; out[aoff + 1] = a1; out[aoff + 2] = a2;
    }
  }
  __syncthreads();
  if (tid < DD) {
    float o = bo[tid];
#pragma unroll
    for (int h = 0; h < HH; ++h) o = fmaf(sw[h], Wo[h * DD + tid], o);
    srow[tid] = o;
  }
  __syncthreads();
  const float4 v = *(const float4*)&srow[(tid & 31) * 4];
  float4* o4 = (float4*)out + (size_t)b * (TT * DD / 4);
#pragma unroll 4
  for (int i = tid; i < TT * DD / 4; i += 256) {
    o4[i] = v;
  }
}

extern "C" void kernel_launch(void* const* d_in, const int* in_sizes, int n_in,
                              void* d_out, int out_size, void* d_ws, size_t ws_size,
                              hipStream_t stream) {
  const float* x    = (const float*)d_in[0];
  const float* ctx  = (const float*)d_in[1];
  const float* W_ih = (const float*)d_in[2];
  const float* W_hh = (const float*)d_in[3];
  const float* b_ih = (const float*)d_in[4];
  const float* b_hh = (const float*)d_in[5];
  const float* Wq   = (const float*)d_in[6];
  const float* bq   = (const float*)d_in[7];
  const float* Ws   = (const float*)d_in[8];
  const float* bs   = (const float*)d_in[9];
  const float* Wo   = (const float*)d_in[10];
  const float* bo   = (const float*)d_in[11];
  const float* logT = (const float*)d_in[12];
  float* out = (float*)d_out;
  const int B = in_sizes[0] / (TT * GG);

  float* hf = (float*)d_ws;  // B*G*H floats

  dim3 g1((B / 32) * GG);
  gru_scan_mfma<<<g1, 128, 0, stream>>>(x, W_ih, W_hh, b_ih, b_hh, hf, B);
  epilogue<<<B, 256, 0, stream>>>(ctx, hf, Wq, bq, Ws, bs, Wo, bo, logT, out, B);
}

// Round 10
// 345.459 us; speedup vs baseline: 1.1031x; 1.1031x over previous
//
#include <hip/hip_runtime.h>
#include <math.h>

#define TT 512
#define GG 3
#define HH 32
#define DD 128

typedef __fp16 fp16x2 __attribute__((ext_vector_type(2)));

__device__ __forceinline__ uint32_t pack2(float a, float b) {
  auto p = __builtin_amdgcn_cvt_pkrtz(a, b);   // __fp16 ext_vector(2)
  return __builtin_bit_cast(uint32_t, p);
}
__device__ __forceinline__ float fdot2u(uint32_t a, uint32_t b, float c) {
  return __builtin_amdgcn_fdot2(__builtin_bit_cast(fp16x2, a),
                                __builtin_bit_cast(fp16x2, b), c, false);
}
__device__ __forceinline__ float fast_tanh(float x) {
  float e = __expf(2.0f * x);
  return 1.0f - 2.0f * __builtin_amdgcn_rcpf(1.0f + e);
}

// 32 lanes per sequence, 8 sequences per 256-thread block -> 768 blocks,
// 3072 waves = 3 waves/SIMD (issue-bound regime, proven by round 1's 98%
// VALUBusy). Lane j owns h[j] and rows {j, 32+j, 64+j} of W_hh as f16 PAIRS
// (log2e scales pre-folded); matvec via v_dot2_f32_f16 (f16 mul, f32 acc).
// h exchanged as f16 through LDS wave-synchronously (no __syncthreads in
// loop); x preloaded to LDS once.
__global__ __launch_bounds__(256, 3) void gru_scan_dot2(
    const float* __restrict__ x, const float* __restrict__ W_ih,
    const float* __restrict__ W_hh, const float* __restrict__ b_ih,
    const float* __restrict__ b_hh, float* __restrict__ hout, int B) {
  const int tid = threadIdx.x;
  const int s = tid >> 5;      // seq-in-block 0..7
  const int j = tid & 31;      // h index owned by this lane
  const int p = blockIdx.x * 8 + s;   // global sequence = b*G + g
  const int g = p % GG;
  const float L2E = 1.44269504088896340736f;

  __shared__ float xs[8][TT + 1];        // x staging (broadcast reads)
  __shared__ uint32_t hb[2][8][20];      // f16-pair h, double buffered

  // ---- cooperative x preload (one-time; lines shared across g) ----
#pragma unroll 4
  for (int i = tid; i < 8 * TT; i += 256) {
    int si = i >> 9, t = i & (TT - 1);
    int pp = blockIdx.x * 8 + si;
    xs[si][t] = x[((size_t)(pp / GG) * TT + t) * GG + (pp % GG)];
  }

  // ---- weights as f16 pairs, log2e-scaled: r,z by -L2E; n by +2L2E ----
  const float* Wg = W_hh + (size_t)g * 3 * HH * HH;
  uint32_t wR[16], wZ[16], wN[16];
#pragma unroll
  for (int m = 0; m < 16; ++m) {
    wR[m] = pack2(Wg[(size_t)j * HH + 2 * m] * (-L2E),
                  Wg[(size_t)j * HH + 2 * m + 1] * (-L2E));
    wZ[m] = pack2(Wg[(size_t)(HH + j) * HH + 2 * m] * (-L2E),
                  Wg[(size_t)(HH + j) * HH + 2 * m + 1] * (-L2E));
    wN[m] = pack2(Wg[(size_t)(2 * HH + j) * HH + 2 * m] * (2.0f * L2E),
                  Wg[(size_t)(2 * HH + j) * HH + 2 * m + 1] * (2.0f * L2E));
  }
  const float wiR2 = W_ih[g * 96 + j] * (-L2E);
  const float wiZ2 = W_ih[g * 96 + 32 + j] * (-L2E);
  const float wiN2 = W_ih[g * 96 + 64 + j] * (2.0f * L2E);
  const float bR2 = (b_ih[g * 96 + j] + b_hh[g * 96 + j]) * (-L2E);
  const float bZ2 = (b_ih[g * 96 + 32 + j] + b_hh[g * 96 + 32 + j]) * (-L2E);
  const float bN2 = b_ih[g * 96 + 64 + j] * (2.0f * L2E);
  const float bHN2 = b_hh[g * 96 + 64 + j] * (2.0f * L2E);

  if (j < 16) hb[0][s][j] = 0u;   // zero h buffer 0
  __syncthreads();                // covers xs + hb init (prologue only)

  float h = 0.0f;

#define STEP(SRC, DST, TC)                                                     \
  {                                                                            \
    float xv = xs[s][TC];                                                      \
    uint4 h0 = *(const uint4*)&hb[SRC][s][0];                                  \
    uint4 h1 = *(const uint4*)&hb[SRC][s][4];                                  \
    uint4 h2 = *(const uint4*)&hb[SRC][s][8];                                  \
    uint4 h3 = *(const uint4*)&hb[SRC][s][12];                                 \
    uint32_t hp[16] = {h0.x, h0.y, h0.z, h0.w, h1.x, h1.y, h1.z, h1.w,         \
                       h2.x, h2.y, h2.z, h2.w, h3.x, h3.y, h3.z, h3.w};        \
    float aR = fmaf(xv, wiR2, bR2), aRb = 0.0f;                                \
    float aZ = fmaf(xv, wiZ2, bZ2), aZb = 0.0f;                                \
    float aN = bHN2, aNb = 0.0f;                                               \
    _Pragma("unroll") for (int m = 0; m < 8; ++m) {                            \
      aR = fdot2u(wR[m], hp[m], aR);                                           \
      aRb = fdot2u(wR[m + 8], hp[m + 8], aRb);                                 \
      aZ = fdot2u(wZ[m], hp[m], aZ);                                           \
      aZb = fdot2u(wZ[m + 8], hp[m + 8], aZb);                                 \
      aN = fdot2u(wN[m], hp[m], aN);                                           \
      aNb = fdot2u(wN[m + 8], hp[m + 8], aNb);                                 \
    }                                                                          \
    float rr = __builtin_amdgcn_rcpf(1.0f + __builtin_amdgcn_exp2f(aR + aRb)); \
    float zz = __builtin_amdgcn_rcpf(1.0f + __builtin_amdgcn_exp2f(aZ + aZb)); \
    float giN = fmaf(xv, wiN2, bN2);                                           \
    float pn = fmaf(rr, aN + aNb, giN);                                        \
    float u = __builtin_amdgcn_rcpf(1.0f + __builtin_amdgcn_exp2f(pn));        \
    float nn = fmaf(-2.0f, u, 1.0f);                                           \
    h = fmaf(zz, h - nn, nn);                                                  \
    ((__fp16*)&hb[DST][s][0])[j] = (__fp16)h;                                  \
    __builtin_amdgcn_wave_barrier();                                           \
  }

#pragma unroll 1
  for (int t = 0; t < TT; t += 2) {
    STEP(0, 1, t)
    STEP(1, 0, t + 1)
  }
#undef STEP

  hout[(size_t)p * HH + j] = h;
}

// One block per b: query -> scores -> softmax -> weighted rep -> out row,
// then broadcast-write the row across all T positions (coalesced float4).
__global__ __launch_bounds__(256) void epilogue(
    const float* __restrict__ ctx, const float* __restrict__ hf,
    const float* __restrict__ Wq, const float* __restrict__ bq,
    const float* __restrict__ Ws, const float* __restrict__ bs,
    const float* __restrict__ Wo, const float* __restrict__ bo,
    const float* __restrict__ logT, float* __restrict__ out, int B) {
  const int b = blockIdx.x;
  const int tid = threadIdx.x;
  __shared__ float sc[DD];
  __shared__ float sw[HH];
  __shared__ float srow[DD];
  if (tid < DD) sc[tid] = ctx[(size_t)b * DD + tid];
  __syncthreads();
  if (tid < HH) {
    float q = bq[tid];
#pragma unroll 4
    for (int d = 0; d < DD; ++d) q = fmaf(sc[d], Wq[d * HH + tid], q);
    float h0 = hf[((size_t)b * 3 + 0) * HH + tid];
    float h1 = hf[((size_t)b * 3 + 1) * HH + tid];
    float h2 = hf[((size_t)b * 3 + 2) * HH + tid];
    float wsv = Ws[tid];
    float s0 = fast_tanh(h0 + q) * wsv;
    float s1 = fast_tanh(h1 + q) * wsv;
    float s2 = fast_tanh(h2 + q) * wsv;
#pragma unroll
    for (int off = 16; off >= 1; off >>= 1) {
      s0 += __shfl_xor(s0, off, 32);
      s1 += __shfl_xor(s1, off, 32);
      s2 += __shfl_xor(s2, off, 32);
    }
    float bsv = bs[0];
    float tmp = fmaxf(__expf(logT[0]), 0.1f);
    float inv = 1.0f / tmp;
    s0 = (s0 + bsv) * inv; s1 = (s1 + bsv) * inv; s2 = (s2 + bsv) * inv;
    float m = fmaxf(s0, fmaxf(s1, s2));
    float e0 = __expf(s0 - m), e1 = __expf(s1 - m), e2 = __expf(s2 - m);
    float den = 1.0f / (e0 + e1 + e2);
    float a0 = e0 * den, a1 = e1 * den, a2 = e2 * den;
    sw[tid] = a0 * h0 + a1 * h1 + a2 * h2;
    if (tid == 0) {
      size_t aoff = (size_t)B * TT * DD + (size_t)b * 3;
      out[aoff] = a0; out[aoff + 1] = a1; out[aoff + 2] = a2;
    }
  }
  __syncthreads();
  if (tid < DD) {
    float o = bo[tid];
#pragma unroll
    for (int h = 0; h < HH; ++h) o = fmaf(sw[h], Wo[h * DD + tid], o);
    srow[tid] = o;
  }
  __syncthreads();
  const float4 v = *(const float4*)&srow[(tid & 31) * 4];
  float4* o4 = (float4*)out + (size_t)b * (TT * DD / 4);
#pragma unroll 4
  for (int i = tid; i < TT * DD / 4; i += 256) {
    o4[i] = v;
  }
}

extern "C" void kernel_launch(void* const* d_in, const int* in_sizes, int n_in,
                              void* d_out, int out_size, void* d_ws, size_t ws_size,
                              hipStream_t stream) {
  const float* x    = (const float*)d_in[0];
  const float* ctx  = (const float*)d_in[1];
  const float* W_ih = (const float*)d_in[2];
  const float* W_hh = (const float*)d_in[3];
  const float* b_ih = (const float*)d_in[4];
  const float* b_hh = (const float*)d_in[5];
  const float* Wq   = (const float*)d_in[6];
  const float* bq   = (const float*)d_in[7];
  const float* Ws   = (const float*)d_in[8];
  const float* bs   = (const float*)d_in[9];
  const float* Wo   = (const float*)d_in[10];
  const float* bo   = (const float*)d_in[11];
  const float* logT = (const float*)d_in[12];
  float* out = (float*)d_out;
  const int B = in_sizes[0] / (TT * GG);

  float* hf = (float*)d_ws;  // B*G*H floats

  dim3 g1((B * GG) / 8);
  gru_scan_dot2<<<g1, 256, 0, stream>>>(x, W_ih, W_hh, b_ih, b_hh, hf, B);
  epilogue<<<B, 256, 0, stream>>>(ctx, hf, Wq, bq, Ws, bs, Wo, bo, logT, out, B);
}